// Round 14
// baseline (119.949 us; speedup 1.0000x reference)
//
#include <hip/hip_runtime.h>
#include <hip/hip_bf16.h>
#include <stdint.h>

// WTA dropout: per image keep values >= k-th largest (k = ceil(N*0.1)), zero rest.
// Round-14: k_count_mask ran at 3.5 TB/s with VGPR_Count=12 -- compiler kept ONE
// outstanding load per wave (latency-serialized). Fix: explicit 8-deep float4
// load batches (8 outstanding loads/wave) before process+store.

#define IMGS    32
#define NPER    1048576             // 2^20 elements per image
#define NPER4   (NPER / 4)          // 2^18 float4 per image
#define NBINS   8192                // 13-bit sample-hist bins
#define BPI     64                  // blocks per image, streaming kernel
#define MARGIN  8192u               // rank margin (6.9 sigma of 1/16-sample error)
#define CAPC    98304               // per-image candidate capacity (~40K worst expected)
#define LCAP    2048                // per-block LDS candidate capacity (~620 expected)
#define CSTRIDE 64                  // counters padded to 256 B apart

typedef float floatx4 __attribute__((ext_vector_type(4)));

__device__ __forceinline__ unsigned mapf(float f) {
    unsigned u = __float_as_uint(f);
    return (u & 0x80000000u) ? ~u : (u | 0x80000000u);   // monotonic float->uint
}

// Block-wide inclusive prefix sum over 256 values (one per thread), result in p[].
__device__ __forceinline__ void block_scan256(unsigned* p, int t, unsigned v) {
    p[t] = v;
    __syncthreads();
    #pragma unroll
    for (int off = 1; off < 256; off <<= 1) {
        unsigned u = (t >= off) ? p[t - off] : 0u;
        __syncthreads();
        p[t] += u;
        __syncthreads();
    }
}

// ---- K1: per-image 1/16 sample hist -> key window [lo,hi); zero counters ----
__global__ void k_sample(const float4* __restrict__ x4, uint2* __restrict__ win,
                         unsigned* __restrict__ cnt_hi, unsigned* __restrict__ candCnt,
                         unsigned k) {
    __shared__ unsigned h[NBINS];               // 32 KB
    __shared__ unsigned pre[256];
    __shared__ unsigned s_hi, s_lo;
    int t = threadIdx.x, img = blockIdx.x;
    if (t == 0) { cnt_hi[img * CSTRIDE] = 0u; candCnt[img * CSTRIDE] = 0u; }
    for (int j = t; j < NBINS; j += 256) h[j] = 0u;
    __syncthreads();

    long long ib = (long long)img * NPER4;
    // 64 chunks of 256 float4 (1024 elems) spread across image: 65536 samples.
    for (int c = 0; c < 16; ++c) {
        float4 a = x4[ib + (long long)(c      ) * 4096 + t];
        float4 b = x4[ib + (long long)(c + 16) * 4096 + t];
        float4 d = x4[ib + (long long)(c + 32) * 4096 + t];
        float4 e = x4[ib + (long long)(c + 48) * 4096 + t];
        atomicAdd(&h[mapf(a.x) >> 19], 1u); atomicAdd(&h[mapf(a.y) >> 19], 1u);
        atomicAdd(&h[mapf(a.z) >> 19], 1u); atomicAdd(&h[mapf(a.w) >> 19], 1u);
        atomicAdd(&h[mapf(b.x) >> 19], 1u); atomicAdd(&h[mapf(b.y) >> 19], 1u);
        atomicAdd(&h[mapf(b.z) >> 19], 1u); atomicAdd(&h[mapf(b.w) >> 19], 1u);
        atomicAdd(&h[mapf(d.x) >> 19], 1u); atomicAdd(&h[mapf(d.y) >> 19], 1u);
        atomicAdd(&h[mapf(d.z) >> 19], 1u); atomicAdd(&h[mapf(d.w) >> 19], 1u);
        atomicAdd(&h[mapf(e.x) >> 19], 1u); atomicAdd(&h[mapf(e.y) >> 19], 1u);
        atomicAdd(&h[mapf(e.z) >> 19], 1u); atomicAdd(&h[mapf(e.w) >> 19], 1u);
    }
    __syncthreads();

    unsigned s = 0;
    #pragma unroll
    for (int j = 0; j < 32; ++j) s += h[t * 32 + ((j + t) & 31)];  // conflict-free
    block_scan256(pre, t, s);
    unsigned above = pre[255] - pre[t];         // sample mass in higher-key chunks

    unsigned tk_hi = (k > MARGIN) ? (k - MARGIN) : 1u;
    unsigned tk_lo = k + MARGIN;
    unsigned tgt_hi = (tk_hi + 15u) >> 4;       // ceil(target_rank / 16)
    unsigned tgt_lo = (tk_lo + 15u) >> 4;

    if (above < tgt_hi && above + s >= tgt_hi) {
        unsigned cum = above;
        for (int j = 31; j >= 0; --j) {
            unsigned v = h[t * 32 + j];
            cum += v;
            if (cum >= tgt_hi) { s_hi = (unsigned)(t * 32 + j); break; }
        }
    }
    if (above < tgt_lo && above + s >= tgt_lo) {
        unsigned cum = above;
        for (int j = 31; j >= 0; --j) {
            unsigned v = h[t * 32 + j];
            cum += v;
            if (cum >= tgt_lo) { s_lo = (unsigned)(t * 32 + j); break; }
        }
    }
    __syncthreads();
    if (t == 0) {
        unsigned shi = s_hi, slo = s_lo;
        if (shi - slo > 15u) slo = shi - 15u;   // window <= 16 bins -> delta < 2^23
        unsigned hi_key = (shi >= 8191u) ? 0xFFFFFFFFu : ((shi + 1u) << 19);
        unsigned lo_key = slo << 19;
        win[img] = make_uint2(lo_key, hi_key);
    }
}

// ---- K2: fused stream (8-deep load pipeline): count + collect + provisional mask
__global__ void k_count_mask(const float4* __restrict__ x4, float4* __restrict__ o4,
                             const uint2* __restrict__ win,
                             unsigned* __restrict__ cnt_hi, unsigned* __restrict__ candCnt,
                             unsigned* __restrict__ candKey, unsigned* __restrict__ candIdx) {
    __shared__ unsigned lkey[LCAP];             // 8 KB
    __shared__ unsigned lidx[LCAP];             // 8 KB
    __shared__ unsigned red[256];
    __shared__ unsigned lcnt, gbase;
    int t = threadIdx.x, bx = blockIdx.x, img = bx >> 6;   // BPI = 64
    if (t == 0) lcnt = 0u;
    __syncthreads();

    uint2 w = win[img];                         // (lo_key, hi_key)
    unsigned c = 0;
    long long base4 = (long long)img * NPER4 + (long long)(bx & 63) * 4096;
    long long i0 = base4 + t;

#define PROC(vv, ii) {                                                        \
        unsigned ka = mapf(vv.x), kb = mapf(vv.y);                            \
        unsigned kc = mapf(vv.z), kd = mapf(vv.w);                            \
        c += ((ka >= w.y) ? 1u : 0u) + ((kb >= w.y) ? 1u : 0u)                \
           + ((kc >= w.y) ? 1u : 0u) + ((kd >= w.y) ? 1u : 0u);               \
        float4 o;                                                             \
        o.x = (ka >= w.x) ? vv.x : 0.0f;                                      \
        o.y = (kb >= w.x) ? vv.y : 0.0f;                                      \
        o.z = (kc >= w.x) ? vv.z : 0.0f;                                      \
        o.w = (kd >= w.x) ? vv.w : 0.0f;                                      \
        unsigned eb = (unsigned)((ii) & (NPER4 - 1)) * 4u;                    \
        if (ka >= w.x && ka < w.y) { unsigned p = atomicAdd(&lcnt, 1u);       \
            if (p < LCAP) { lkey[p] = ka; lidx[p] = eb; } }                   \
        if (kb >= w.x && kb < w.y) { unsigned p = atomicAdd(&lcnt, 1u);       \
            if (p < LCAP) { lkey[p] = kb; lidx[p] = eb + 1u; } }              \
        if (kc >= w.x && kc < w.y) { unsigned p = atomicAdd(&lcnt, 1u);       \
            if (p < LCAP) { lkey[p] = kc; lidx[p] = eb + 2u; } }              \
        if (kd >= w.x && kd < w.y) { unsigned p = atomicAdd(&lcnt, 1u);       \
            if (p < LCAP) { lkey[p] = kd; lidx[p] = eb + 3u; } }              \
        floatx4 ov = { o.x, o.y, o.z, o.w };                                  \
        __builtin_nontemporal_store(ov, (floatx4*)&o4[ii]);                   \
    }

    #pragma unroll
    for (int it = 0; it < 16; it += 8) {
        // 8 independent loads in flight before first use (vmcnt(7))
        float4 v0 = x4[i0 + (it + 0) * 256];
        float4 v1 = x4[i0 + (it + 1) * 256];
        float4 v2 = x4[i0 + (it + 2) * 256];
        float4 v3 = x4[i0 + (it + 3) * 256];
        float4 v4 = x4[i0 + (it + 4) * 256];
        float4 v5 = x4[i0 + (it + 5) * 256];
        float4 v6 = x4[i0 + (it + 6) * 256];
        float4 v7 = x4[i0 + (it + 7) * 256];
        PROC(v0, i0 + (it + 0) * 256); PROC(v1, i0 + (it + 1) * 256);
        PROC(v2, i0 + (it + 2) * 256); PROC(v3, i0 + (it + 3) * 256);
        PROC(v4, i0 + (it + 4) * 256); PROC(v5, i0 + (it + 5) * 256);
        PROC(v6, i0 + (it + 6) * 256); PROC(v7, i0 + (it + 7) * 256);
    }
#undef PROC

    red[t] = c;
    __syncthreads();
    for (int off = 128; off > 0; off >>= 1) {
        if (t < off) red[t] += red[t + off];
        __syncthreads();
    }
    unsigned n = lcnt;
    if (n > LCAP) n = LCAP;
    if (t == 0) {
        atomicAdd(&cnt_hi[img * CSTRIDE], red[0]);
        gbase = atomicAdd(&candCnt[img * CSTRIDE], n);
    }
    __syncthreads();
    unsigned gb = gbase;
    long long cb = (long long)img * CAPC;
    for (unsigned j = t; j < n; j += 256u) {
        unsigned pos = gb + j;
        if (pos < CAPC) {
            candKey[cb + pos] = lkey[j];
            candIdx[cb + pos] = lidx[j];
        }
    }
}

// ---- K3: 2-round radix select on delta = key - lo (11 + 12 bits) ------------
__global__ void k_select(const uint2* __restrict__ win,
                         const unsigned* __restrict__ cnt_hi,
                         const unsigned* __restrict__ candCnt,
                         const unsigned* __restrict__ candKey,
                         unsigned* __restrict__ thrArr, unsigned k) {
    int img = blockIdx.x, t = threadIdx.x;
    __shared__ unsigned h2[4096];               // 16 KB
    __shared__ unsigned pre[256];
    __shared__ unsigned sbin, srank;

    unsigned n = candCnt[img * CSTRIDE];
    if (n > CAPC) n = CAPC;
    unsigned chi = cnt_hi[img * CSTRIDE];
    unsigned r = (k > chi) ? (k - chi) : 1u;    // rank among window keys
    if (r > n) r = n;                           // safety clamp
    unsigned lo = win[img].x;
    const uint4* ck4 = (const uint4*)(candKey + (long long)img * CAPC);
    unsigned n4 = (n + 3u) >> 2;

    // rounds on delta (< 2^23): [22:12] 2048 bins, then [11:0] 4096 bins
    unsigned pfx = 0u;
    for (int rd = 0; rd < 2; ++rd) {
        int bins = rd == 0 ? 2048 : 4096;
        int sh = rd == 0 ? 12 : 0;
        for (int j = t; j < bins; j += 256) h2[j] = 0u;
        __syncthreads();
        unsigned bmask = (unsigned)bins - 1u;
        for (unsigned j = t; j < n4; j += 256u) {
            uint4 kk = ck4[j];                  // 16B coalesced, pipelineable
            unsigned base = j * 4u;
            unsigned kw[4] = {kk.x, kk.y, kk.z, kk.w};
            #pragma unroll
            for (int c2 = 0; c2 < 4; ++c2) {
                if (base + (unsigned)c2 < n) {
                    unsigned delta = kw[c2] - lo;        // < 2^23 (window clamp)
                    bool ok = (rd == 0) || ((delta >> 12) == pfx);
                    if (ok) atomicAdd(&h2[(delta >> sh) & bmask], 1u);
                }
            }
        }
        __syncthreads();

        int bpt = bins >> 8;                    // bins per thread: 8, 16
        unsigned s = 0;
        for (int j = 0; j < bpt; ++j) s += h2[t * bpt + ((j + t) & (bpt - 1))];
        block_scan256(pre, t, s);
        unsigned above = pre[255] - pre[t];
        if (above < r && above + s >= r) {
            unsigned cum = above;
            for (int j = bpt - 1; j >= 0; --j) {
                unsigned v = h2[t * bpt + j];
                cum += v;
                if (cum >= r) {
                    sbin = (unsigned)(t * bpt + j);
                    srank = r - (cum - v);
                    break;
                }
            }
        }
        __syncthreads();
        pfx = (rd == 0) ? sbin : ((pfx << 12) | sbin);
        r = srank;
        __syncthreads();
    }
    if (t == 0) thrArr[img] = lo + pfx;         // exact key of k-th largest
}

// ---- K4: full-grid fixup: zero candidates with key < thr --------------------
__global__ void k_fixup(float* __restrict__ out, const unsigned* __restrict__ thrArr,
                        const unsigned* __restrict__ candCnt,
                        const unsigned* __restrict__ candKey,
                        const unsigned* __restrict__ candIdx) {
    int bx = blockIdx.x, t = threadIdx.x, img = bx >> 6;   // BPI = 64
    unsigned n = candCnt[img * CSTRIDE];
    if (n > CAPC) n = CAPC;
    unsigned thr = thrArr[img];
    const unsigned* ck = candKey + (long long)img * CAPC;
    const unsigned* ci = candIdx + (long long)img * CAPC;
    float* oi = out + (long long)img * NPER;
    for (unsigned j = (unsigned)(bx & 63) * 256u + t; j < n; j += 64u * 256u) {
        if (ck[j] < thr) oi[ci[j]] = 0.0f;
    }
}

extern "C" void kernel_launch(void* const* d_in, const int* in_sizes, int n_in,
                              void* d_out, int out_size, void* d_ws, size_t ws_size,
                              hipStream_t stream) {
    const float* x = (const float*)d_in[0];
    float* out = (float*)d_out;
    unsigned k = (unsigned)((NPER + 9) / 10);         // ceil(N*0.1) = 104858

    // workspace layout (~24 MB total)
    char* ws = (char*)d_ws;
    size_t padB = (size_t)IMGS * CSTRIDE * 4;         // 8 KB each
    unsigned* cnt_hi  = (unsigned*)ws;
    unsigned* candCnt = (unsigned*)(ws + padB);
    uint2*    win     = (uint2*)   (ws + 2 * padB);   // 256 B
    unsigned* thrArr  = (unsigned*)(ws + 2 * padB + 1024);
    unsigned* candKey = (unsigned*)(ws + 2 * padB + 2048);               // 12 MB
    unsigned* candIdx = (unsigned*)(ws + 2 * padB + 2048
                                       + (size_t)IMGS * CAPC * 4);       // 12 MB

    dim3 blk(256);
    k_sample<<<dim3(IMGS), blk, 0, stream>>>((const float4*)x, win, cnt_hi, candCnt, k);
    k_count_mask<<<dim3(IMGS * BPI), blk, 0, stream>>>((const float4*)x, (float4*)out,
                                                       win, cnt_hi, candCnt,
                                                       candKey, candIdx);
    k_select<<<dim3(IMGS), blk, 0, stream>>>(win, cnt_hi, candCnt, candKey, thrArr, k);
    k_fixup<<<dim3(IMGS * BPI), blk, 0, stream>>>(out, thrArr, candCnt, candKey, candIdx);
}